// Round 13
// baseline (90.594 us; speedup 1.0000x reference)
//
#include <hip/hip_runtime.h>

// out[b,o,h,w] = sum_{c,k} (coef[k]/12.5) * rint( sum_j (12.5*w[k,c,o,j])*x_j + 12.5*b[k,c,o] )
// R13 = R12 schedule (70.5us: 4-way c-split, 4 waves/block, XCD-keyed grid, x ping-pong,
//       [o][c][k][10] weights, LDS combine) with a SCALAR-FMAC body:
//       v_fmac_f32 vdst, s_w, v_x  (VOP2, weight from SGPR) -> zero v2f packing/splat movs.
//       FMA-pipe time unchanged; kills ~120 cyc/c of mov fat (534 -> ~410 cyc/c).

#define NB     8
#define NC     32
#define NO     32
#define NH     64
#define NW     64
#define NBATCH 8
#define FST    10                  // 9 taps + bias
#define PLANE  (NH * NW)
#define WCSTEP (NB * FST)          // dwords per c step in wq (contiguous per-o stream)
#define CQUART 8                   // channels per wave

// wq layout: [o:32][c:32][k:8][10]; value = 12.5*w, [9] = 12.5*bias
__global__ void prep_wq(const float* __restrict__ w, const float* __restrict__ bias,
                        float* __restrict__ wq) {
    int idx = blockIdx.x * 256 + threadIdx.x;      // (o*32+c)*8+k
    if (idx >= NC * NO * NB) return;
    int k = idx & 7;
    int c = (idx >> 3) & 31;
    int o = idx >> 8;
    int ch = c * NO + o;                           // channel in original [k][1024] layout
    const float* ws = w + ((size_t)k * (NC * NO) + ch) * 9;
    float* dst = wq + (size_t)idx * FST;
#pragma unroll
    for (int j = 0; j < 9; ++j) dst[j] = 12.5f * ws[j];
    dst[9] = 12.5f * bias[k * (NC * NO) + ch];
}

// lane w receives lane w-1's value; lane 0 -> 0 (bound_ctrl). (wave_shr:1 = 0x138)
__device__ __forceinline__ float dpp_left(float v) {
    return __builtin_bit_cast(float, __builtin_amdgcn_update_dpp(
        0, __builtin_bit_cast(int, v), 0x138, 0xf, 0xf, true));
}
// lane w receives lane w+1's value; lane 63 -> 0. (wave_shl:1 = 0x130)
__device__ __forceinline__ float dpp_right(float v) {
    return __builtin_bit_cast(float, __builtin_amdgcn_update_dpp(
        0, __builtin_bit_cast(int, v), 0x130, 0xf, 0xf, true));
}

// One channel-step, scalar form. Tap/FMA order identical to R8..R12 (absmax canary).
// acc0 = output row h0, acc1 = output row h0+1.
__device__ __forceinline__ void step(float xm1, float x0, float x1, float x2,
                                     bool top, bool bot,
                                     const float* __restrict__ wp,
                                     float& acc0, float& acc1,
                                     const float* __restrict__ ckq) {
    if (!top) xm1 = 0.f;                           // wave-uniform
    if (!bot) x2  = 0.f;

    float lm1 = dpp_left(xm1), l0 = dpp_left(x0), l1 = dpp_left(x1), l2 = dpp_left(x2);
    float rm1 = dpp_right(xm1), r0 = dpp_right(x0), r1 = dpp_right(x1), r2 = dpp_right(x2);

#pragma unroll
    for (int k = 0; k < NB; ++k) {
        const float* f = wp + k * FST;             // SGPR base + compile-time imm offsets
        float s0 = f[9], s1 = f[9];                // pre-scaled bias (both rows)
        // row h0 taps:   (lm1,xm1,rm1, l0,x0,r0, l1,x1,r1)
        // row h0+1 taps: (l0, x0, r0,  l1,x1,r1, l2,x2,r2)
        s0 = fmaf(f[0], lm1, s0);  s1 = fmaf(f[0], l0, s1);
        s0 = fmaf(f[1], xm1, s0);  s1 = fmaf(f[1], x0, s1);
        s0 = fmaf(f[2], rm1, s0);  s1 = fmaf(f[2], r0, s1);
        s0 = fmaf(f[3], l0,  s0);  s1 = fmaf(f[3], l1, s1);
        s0 = fmaf(f[4], x0,  s0);  s1 = fmaf(f[4], x1, s1);
        s0 = fmaf(f[5], r0,  s0);  s1 = fmaf(f[5], r1, s1);
        s0 = fmaf(f[6], l1,  s0);  s1 = fmaf(f[6], l2, s1);
        s0 = fmaf(f[7], x1,  s0);  s1 = fmaf(f[7], x2, s1);
        s0 = fmaf(f[8], r1,  s0);  s1 = fmaf(f[8], r2, s1);
        acc0 = fmaf(ckq[k], rintf(s0), acc0);
        acc1 = fmaf(ckq[k], rintf(s1), acc1);
    }
}

// Block = 4 waves (256 thr) = one (b, o, row-pair) x 4 c-quarters.
// Grid (8 hb, o*4+hsub, b): dispatch id % 8 == hb (XCD key); same-o blocks burst per XCD.
__global__ __launch_bounds__(256, 8) void demolition_conv(
        const float* __restrict__ x, const float* __restrict__ wq,
        float* __restrict__ out) {
    __shared__ float part[3][2][64];               // written by cq=1..3

    const int tid  = threadIdx.x;
    const int w    = tid & 63;
    const int cq   = tid >> 6;                     // 0..3 (c-quarter)
    const int hb   = blockIdx.x;                   // 0..7 (XCD key)
    const int o    = blockIdx.y >> 2;              // 0..31
    const int hsub = blockIdx.y & 3;               // 0..3
    const int b    = blockIdx.z;
    const int h0   = hb * 8 + hsub * 2;            // 0..62 even

    const float ckq[8] = {
        -128.f / 127.f / 12.5f,  1.f / 127.f / 12.5f,  2.f / 127.f / 12.5f,
           4.f / 127.f / 12.5f,  8.f / 127.f / 12.5f, 16.f / 127.f / 12.5f,
          32.f / 127.f / 12.5f, 64.f / 127.f / 12.5f };

    float acc0 = 0.f, acc1 = 0.f;

    const bool top = (h0 > 0), bot = (h0 < NH - 2);   // wave-uniform
    const int  rT  = top ? -NW : 0;        // clamped address for row h0-1
    const int  rB  = bot ? 2 * NW : NW;    // clamped address for row h0+2

    const float* xc = x + (((size_t)b * NC + cq * CQUART) * NH + h0) * NW + w;
    const float* wp = wq + __builtin_amdgcn_readfirstlane(
                          o * (NC * NB * FST) + cq * CQUART * WCSTEP);

    // prologue: raw loads for first channel (ping)
    float am1 = xc[rT], a0 = xc[0], a1 = xc[NW], a2 = xc[rB];

#pragma unroll 1
    for (int c = 0; c < CQUART; c += 2) {
        // prefetch c+1 (pong) — issued BEFORE compute of c
        const float* xn = xc + PLANE;
        float bm1 = xn[rT], b0 = xn[0], b1 = xn[NW], b2 = xn[rB];
        step(am1, a0, a1, a2, top, bot, wp, acc0, acc1, ckq);
        wp += WCSTEP;

        // prefetch c+2 (ping); clamp at tail (wave-uniform, loads harmless & unused)
        const float* xm = (c + 2 < CQUART) ? xn + PLANE : xn;
        am1 = xm[rT]; a0 = xm[0]; a1 = xm[NW]; a2 = xm[rB];
        step(bm1, b0, b1, b2, top, bot, wp, acc0, acc1, ckq);
        wp += WCSTEP;

        xc = xm;
    }

    // combine the four c-quarters (post-rint partials; outer-sum reassociation only)
    if (cq) {
        part[cq - 1][0][w] = acc0;
        part[cq - 1][1][w] = acc1;
    }
    __syncthreads();
    if (!cq) {
        float* op = out + (((size_t)b * NO + o) * NH + h0) * NW + w;
        op[0]  = acc0 + part[0][0][w] + part[1][0][w] + part[2][0][w];
        op[NW] = acc1 + part[0][1][w] + part[1][1][w] + part[2][1][w];
    }
}

extern "C" void kernel_launch(void* const* d_in, const int* in_sizes, int n_in,
                              void* d_out, int out_size, void* d_ws, size_t ws_size,
                              hipStream_t stream) {
    const float* x    = (const float*)d_in[0];   // [8,32,64,64]
    const float* wt   = (const float*)d_in[1];   // [8,1024,1,3,3]
    const float* bias = (const float*)d_in[2];   // [8,1024]
    float* out = (float*)d_out;                  // [8,32,64,64]
    float* wq  = (float*)d_ws;                   // 8192*10 floats = 320 KiB

    prep_wq<<<(NC * NO * NB + 255) / 256, 256, 0, stream>>>(wt, bias, wq);

    dim3 grid(8, NO * 4, NBATCH);                // (hb, o*4+hsub, b): id % 8 == hb (XCD key)
    demolition_conv<<<grid, 256, 0, stream>>>(x, wq, out);
}